// Round 4
// baseline (212.634 us; speedup 1.0000x reference)
//
#include <hip/hip_runtime.h>
#include <math.h>

// ---- problem constants ----
#define NN      4096   // nodes
#define INF_    512    // in features
#define OUTF    256    // out features
#define NHEAD   4
#define HDIM    64
#define KSPLIT  4

typedef __attribute__((ext_vector_type(8))) short  short8x;
typedef __attribute__((ext_vector_type(4))) float  float4x;
typedef __attribute__((ext_vector_type(2))) float  float2x;

__device__ __forceinline__ unsigned short f2bf(float x) {
    union { float f; unsigned int u; } c; c.f = x;
    unsigned int r = (c.u + 0x7FFFu + ((c.u >> 16) & 1u)) >> 16;
    return (unsigned short)r;
}
// pack 2 fp32 -> 2 bf16 in one dword (RNE, identical to f2bf)
__device__ __forceinline__ unsigned int cvtpk_bf16(float lo, float hi) {
    unsigned int r;
    asm("v_cvt_pk_bf16_f32 %0, %1, %2" : "=v"(r) : "v"(lo), "v"(hi));
    return r;
}
// unpack a bf16 pair (one dword) into float2 {lo, hi}
__device__ __forceinline__ float2x bf2up(unsigned int u) {
    union { unsigned int x; float f; } lo, hi;
    lo.x = u << 16; hi.x = u & 0xFFFF0000u;
    float2x r; r[0] = lo.f; r[1] = hi.f; return r;
}
__device__ __forceinline__ float2x max2(float2x a, float2x b) {
    float2x r; r[0] = fmaxf(a[0], b[0]); r[1] = fmaxf(a[1], b[1]); return r;
}

// ============================================================
// K0: cast feat and W to bf16; init out = bias (for split-K atomics)
// ============================================================
__global__ __launch_bounds__(256) void k_cast(const float* __restrict__ feat,
                                              const float* __restrict__ W,
                                              const float* __restrict__ bias,
                                              unsigned short* __restrict__ featb,
                                              unsigned short* __restrict__ Wb,
                                              float* __restrict__ out) {
    const int b = blockIdx.x;
    const int tid = threadIdx.x;
    if (b >= 2176) {
        // bias-init: rows of out = bias  (1024 blocks x 1024 floats)
        int idx = (b - 2176) * 1024 + tid * 4;
        float4x bv = *(const float4x*)(bias + ((tid * 4) & 255));
        *(float4x*)(out + idx) = bv;
        return;
    }
    const float* src;
    unsigned short* dst;
    int idx;
    if (b < 2048) { src = feat; dst = featb; idx = b * 1024 + tid * 4; }
    else          { src = W;    dst = Wb;    idx = (b - 2048) * 1024 + tid * 4; }
    float4x v = *(const float4x*)(src + idx);
    ushort4 u;
    u.x = f2bf(v[0]); u.y = f2bf(v[1]); u.z = f2bf(v[2]); u.w = f2bf(v[3]);
    *(ushort4*)(dst + idx) = u;
}

// ============================================================
// K1: h = feat @ W^T (bf16 MFMA, 32-row tiles -> 128 blocks)
// epilogue: hT bf16 write + es/ed per-head dots from registers
// -> es + exp tables Bt=exp(ed), Dt=exp(0.2 ed)
// ============================================================
__global__ __launch_bounds__(256) void k_hedge(const unsigned short* __restrict__ featb,
                                               const unsigned short* __restrict__ Wb,
                                               const float* __restrict__ a,
                                               unsigned short* __restrict__ hT,
                                               float* __restrict__ es,
                                               unsigned short* __restrict__ Bt,
                                               unsigned short* __restrict__ Dt) {
    __shared__ __align__(16) unsigned short lds_f[32 * 40];
    __shared__ __align__(16) unsigned short lds_w[256 * 40];
    const int tid  = threadIdx.x;
    const int w    = tid >> 6;
    const int lane = tid & 63;
    const int lidx = lane & 15;
    const int quad = lane >> 4;
    const int i0   = blockIdx.x * 32;
    const int srf  = tid >> 3;          // 0..31
    const int skf  = (tid & 7) * 4;     // 0..28
    const int srw  = tid >> 2;          // 0..63
    const int skw  = (tid & 3) * 8;

    float4x acc[2][4];
    #pragma unroll
    for (int p = 0; p < 2; ++p)
        #pragma unroll
        for (int q = 0; q < 4; ++q)
            acc[p][q] = (float4x){0.f, 0.f, 0.f, 0.f};

    for (int kt = 0; kt < INF_; kt += 32) {
        __syncthreads();
        *(ushort4*)&lds_f[srf * 40 + skf] = *(const ushort4*)&featb[(size_t)(i0 + srf) * INF_ + kt + skf];
        #pragma unroll
        for (int itr = 0; itr < 4; ++itr) {
            int n = itr * 64 + srw;
            *(ushort4*)&lds_w[n * 40 + skw]     = *(const ushort4*)&Wb[(size_t)n * INF_ + kt + skw];
            *(ushort4*)&lds_w[n * 40 + skw + 4] = *(const ushort4*)&Wb[(size_t)n * INF_ + kt + skw + 4];
        }
        __syncthreads();
        short8x af[2], bw[4];
        #pragma unroll
        for (int t = 0; t < 2; ++t)
            af[t] = *(const short8x*)&lds_f[(t * 16 + lidx) * 40 + quad * 8];
        #pragma unroll
        for (int t = 0; t < 4; ++t)
            bw[t] = *(const short8x*)&lds_w[(w * 64 + t * 16 + lidx) * 40 + quad * 8];
        #pragma unroll
        for (int it = 0; it < 2; ++it)
            #pragma unroll
            for (int nt = 0; nt < 4; ++nt)
                acc[it][nt] = __builtin_amdgcn_mfma_f32_16x16x32_bf16(
                    af[it], bw[nt], acc[it][nt], 0, 0, 0);
    }
    // ---- hT write (D layout: col=lane&15 block w*64+nt*16, row=quad*4+r) ----
    #pragma unroll
    for (int it = 0; it < 2; ++it)
        #pragma unroll
        for (int nt = 0; nt < 4; ++nt) {
            int col = w * 64 + nt * 16 + lidx;
            int m0r = i0 + it * 16 + quad * 4;
            uint2 u;
            u.x = cvtpk_bf16(acc[it][nt][0], acc[it][nt][1]);
            u.y = cvtpk_bf16(acc[it][nt][2], acc[it][nt][3]);
            *(uint2*)&hT[(size_t)col * NN + m0r] = u;
        }
    // ---- es/ed epilogue: head = w; col_d = nt*16 + lidx ----
    float asrc[4], adst[4];
    #pragma unroll
    for (int nt = 0; nt < 4; ++nt) {
        asrc[nt] = a[w * 2 * HDIM + nt * 16 + lidx];
        adst[nt] = a[w * 2 * HDIM + HDIM + nt * 16 + lidx];
    }
    #pragma unroll
    for (int it = 0; it < 2; ++it)
        #pragma unroll
        for (int r = 0; r < 4; ++r) {
            float s = 0.f, d = 0.f;
            #pragma unroll
            for (int nt = 0; nt < 4; ++nt) {
                s += acc[it][nt][r] * asrc[nt];
                d += acc[it][nt][r] * adst[nt];
            }
            #pragma unroll
            for (int off = 1; off < 16; off <<= 1) {
                s += __shfl_xor(s, off);
                d += __shfl_xor(d, off);
            }
            if (lidx == 0) {
                int row = i0 + it * 16 + quad * 4 + r;
                es[row * NHEAD + w] = s;
                Bt[row * NHEAD + w] = f2bf(__expf(d));
                Dt[row * NHEAD + w] = f2bf(__expf(0.2f * d));
            }
        }
}

// ============================================================
// K2: fused den + attn-row write. 1 row/block, 4096 blocks.
// Max-trick: exp(leaky(es+ed)) = max(A*b, C*d). Pass 1 computes
// masked per-head terms m_h = mask*max(A*b, C*d) and KEEPS THEM
// IN REGISTERS. Pass 2 is a pure register dot with sc[h] =
// 0.25/den[h] -- zero table re-reads; cvt_pk bf16 pack.
// ============================================================
__global__ __launch_bounds__(256) void k_attn(const float* __restrict__ adj,
                                              const float* __restrict__ es,
                                              const unsigned short* __restrict__ Bt,
                                              const unsigned short* __restrict__ Dt,
                                              unsigned short* __restrict__ attn) {
    __shared__ float red[4][4];
    __shared__ float cfs[4];
    const int tid = threadIdx.x;
    const int wv  = tid >> 6;
    const int lane = tid & 63;
    const int i = blockIdx.x;

    const float4x esv = ((const float4x*)es)[i];
    float2x A01, A23, C01, C23;
    A01[0] = __expf(esv[0]); A01[1] = __expf(esv[1]);
    A23[0] = __expf(esv[2]); A23[1] = __expf(esv[3]);
    C01[0] = __expf(0.2f * esv[0]); C01[1] = __expf(0.2f * esv[1]);
    C23[0] = __expf(0.2f * esv[2]); C23[1] = __expf(0.2f * esv[3]);

    const float4x* arow4 = (const float4x*)(adj + (size_t)i * NN);
    const uint4* B4 = (const uint4*)Bt;
    const uint4* D4 = (const uint4*)Dt;

    // ---- pass 1: masked per-head terms -> registers; accumulate den ----
    float2x m01[4][4], m23[4][4];
    float2x den01 = (float2x){0.f, 0.f};
    float2x den23 = (float2x){0.f, 0.f};
    #pragma unroll
    for (int t = 0; t < 4; ++t) {
        int jv = t * 256 + tid;
        float4x av = arow4[jv];
        uint4 bu0 = B4[jv * 2], bu1 = B4[jv * 2 + 1];
        uint4 du0 = D4[jv * 2], du1 = D4[jv * 2 + 1];
        unsigned int bwv[8] = {bu0.x, bu0.y, bu0.z, bu0.w, bu1.x, bu1.y, bu1.z, bu1.w};
        unsigned int dwv[8] = {du0.x, du0.y, du0.z, du0.w, du1.x, du1.y, du1.z, du1.w};
        #pragma unroll
        for (int u = 0; u < 4; ++u) {
            float2x b01 = bf2up(bwv[u * 2]);
            float2x b23 = bf2up(bwv[u * 2 + 1]);
            float2x d01 = bf2up(dwv[u * 2]);
            float2x d23 = bf2up(dwv[u * 2 + 1]);
            float mf = (av[u] > 0.1f) ? 1.f : 0.f;
            float2x mf2; mf2[0] = mf; mf2[1] = mf;
            m01[t][u] = mf2 * max2(A01 * b01, C01 * d01);
            m23[t][u] = mf2 * max2(A23 * b23, C23 * d23);
            den01 += m01[t][u];
            den23 += m23[t][u];
        }
    }
    float dh[4] = {den01[0], den01[1], den23[0], den23[1]};
    #pragma unroll
    for (int off = 1; off < 64; off <<= 1) {
        #pragma unroll
        for (int h = 0; h < 4; ++h)
            dh[h] += __shfl_xor(dh[h], off);
    }
    if (lane == 0) {
        #pragma unroll
        for (int h = 0; h < 4; ++h) red[wv][h] = dh[h];
    }
    __syncthreads();
    if (tid < 4)
        cfs[tid] = red[0][tid] + red[1][tid] + red[2][tid] + red[3][tid];
    __syncthreads();
    float sc[4];
    #pragma unroll
    for (int h = 0; h < 4; ++h) {
        float den = cfs[h];
        sc[h] = den > 0.f ? 0.25f / den : 0.f;
    }

    // ---- pass 2: pure register dot, cvt_pk pack, store ----
    unsigned short* orow = attn + (size_t)i * NN;
    #pragma unroll
    for (int t = 0; t < 4; ++t) {
        int jv = t * 256 + tid;
        float pv[4];
        #pragma unroll
        for (int u = 0; u < 4; ++u) {
            pv[u] = sc[0] * m01[t][u][0] + sc[1] * m01[t][u][1]
                  + sc[2] * m23[t][u][0] + sc[3] * m23[t][u][1];
        }
        uint2 o;
        o.x = cvtpk_bf16(pv[0], pv[1]);
        o.y = cvtpk_bf16(pv[2], pv[3]);
        *(uint2*)&orow[jv * 4] = o;
    }
}

// ============================================================
// K3: split-K GEMM, NO LDS -- operand layouts are fragment-shaped
// in global memory (attn row-major-in-k, hT [col][row]); each
// lane loads its 16B fragment directly (4 quads cover a full 64B
// line -> coalesced; hT is L2-resident). Register double-buffered
// 64-k chunks, fully unrolled (static buffer indices). Zero
// barriers, zero bank conflicts. 16-row tiles, grid (256, 4) =
// 1024 blocks = 4 blocks/CU. atomicAdd into bias-initialized out.
// ============================================================
__global__ __launch_bounds__(256, 4) void k_out_gemm(const unsigned short* __restrict__ attn,
                                                     const unsigned short* __restrict__ hT,
                                                     float* __restrict__ out) {
    const int tid  = threadIdx.x;
    const int w    = tid >> 6;
    const int lane = tid & 63;
    const int lidx = lane & 15;
    const int quad = lane >> 4;
    const int i0    = blockIdx.x * 16;
    const int kbase = blockIdx.y * (NN / KSPLIT);   // 1024-wide k slice

    const unsigned short* arow = attn + (size_t)(i0 + lidx) * NN + kbase + quad * 8;
    const unsigned short* hrow = hT   + (size_t)(w * 64 + lidx) * NN + kbase + quad * 8;

    float4x acc[4];
    #pragma unroll
    for (int q = 0; q < 4; ++q)
        acc[q] = (float4x){0.f, 0.f, 0.f, 0.f};

    short8x ab[2][2];       // [buf][k-half]
    short8x bb[2][8];       // [buf][col-tile*2 + k-half]

    // prologue: chunk 0
    #pragma unroll
    for (int hh = 0; hh < 2; ++hh) {
        ab[0][hh] = *(const short8x*)(arow + hh * 32);
        #pragma unroll
        for (int t = 0; t < 4; ++t)
            bb[0][t * 2 + hh] = *(const short8x*)(hrow + (size_t)t * 16 * NN + hh * 32);
    }

    const int NCHUNK = (NN / KSPLIT) / 64;   // 16
    #pragma unroll
    for (int it = 0; it < NCHUNK; ++it) {
        const int cur = it & 1, nxt = cur ^ 1;
        if (it + 1 < NCHUNK) {
            const int ko = (it + 1) * 64;
            #pragma unroll
            for (int hh = 0; hh < 2; ++hh) {
                ab[nxt][hh] = *(const short8x*)(arow + ko + hh * 32);
                #pragma unroll
                for (int t = 0; t < 4; ++t)
                    bb[nxt][t * 2 + hh] = *(const short8x*)(hrow + (size_t)t * 16 * NN + ko + hh * 32);
            }
        }
        #pragma unroll
        for (int hh = 0; hh < 2; ++hh)
            #pragma unroll
            for (int nt = 0; nt < 4; ++nt)
                acc[nt] = __builtin_amdgcn_mfma_f32_16x16x32_bf16(
                    ab[cur][hh], bb[cur][nt * 2 + hh], acc[nt], 0, 0, 0);
    }

    #pragma unroll
    for (int nt = 0; nt < 4; ++nt)
        #pragma unroll
        for (int rr = 0; rr < 4; ++rr) {
            int row = i0 + quad * 4 + rr;
            int col = w * 64 + nt * 16 + lidx;
            unsafeAtomicAdd(&out[(size_t)row * OUTF + col], acc[nt][rr]);
        }
}

// ============================================================
extern "C" void kernel_launch(void* const* d_in, const int* in_sizes, int n_in,
                              void* d_out, int out_size, void* d_ws, size_t ws_size,
                              hipStream_t stream) {
    const float* feat = (const float*)d_in[0];   // [4096,512]
    const float* adj  = (const float*)d_in[1];   // [4096,4096]
    const float* W    = (const float*)d_in[2];   // [256,512]
    const float* a    = (const float*)d_in[3];   // [4,128]
    const float* bias = (const float*)d_in[4];   // [256]
    float* out = (float*)d_out;                  // [4096,256] fp32

    char* ws = (char*)d_ws;
    float*          es    = (float*)(ws + 0);                        // 64 KiB
    unsigned short* Btb   = (unsigned short*)(ws + (64u << 10));     // 32 KiB
    unsigned short* Dtb   = (unsigned short*)(ws + (96u << 10));     // 32 KiB
    unsigned short* hT    = (unsigned short*)(ws + (256u << 10));    // 2 MiB
    unsigned short* attn  = (unsigned short*)(ws + (2560u << 10));   // 32 MiB
    unsigned short* featb = (unsigned short*)(ws + (2560u << 10));   // 4 MiB (dead before attn written)
    unsigned short* Wb    = (unsigned short*)(ws + (6656u << 10));   // 256 KiB (dead before attn)

    k_cast      <<<3200,              256, 0, stream>>>(feat, W, bias, featb, Wb, out);
    k_hedge     <<<128,               256, 0, stream>>>(featb, Wb, a, hT, es, Btb, Dtb);
    k_attn      <<<NN,                256, 0, stream>>>(adj, es, Btb, Dtb, attn);
    k_out_gemm  <<<dim3(256, KSPLIT), 256, 0, stream>>>(attn, hT, out);
}

// Round 6
// 189.407 us; speedup vs baseline: 1.1226x; 1.1226x over previous
//
#include <hip/hip_runtime.h>
#include <math.h>

// ---- problem constants ----
#define NN      4096   // nodes
#define INF_    512    // in features
#define OUTF    256    // out features
#define NHEAD   4
#define HDIM    64
#define KSPLIT  8

typedef __attribute__((ext_vector_type(8))) short  short8x;
typedef __attribute__((ext_vector_type(4))) float  float4x;
typedef __attribute__((ext_vector_type(2))) float  float2x;

__device__ __forceinline__ unsigned short f2bf(float x) {
    union { float f; unsigned int u; } c; c.f = x;
    unsigned int r = (c.u + 0x7FFFu + ((c.u >> 16) & 1u)) >> 16;
    return (unsigned short)r;
}
// pack 2 fp32 -> 2 bf16 in one dword (RNE, identical to f2bf)
__device__ __forceinline__ unsigned int cvtpk_bf16(float lo, float hi) {
    unsigned int r;
    asm("v_cvt_pk_bf16_f32 %0, %1, %2" : "=v"(r) : "v"(lo), "v"(hi));
    return r;
}
// unpack a bf16 pair (one dword) into float2 {lo, hi}
__device__ __forceinline__ float2x bf2up(unsigned int u) {
    union { unsigned int x; float f; } lo, hi;
    lo.x = u << 16; hi.x = u & 0xFFFF0000u;
    float2x r; r[0] = lo.f; r[1] = hi.f; return r;
}
__device__ __forceinline__ float2x max2(float2x a, float2x b) {
    float2x r; r[0] = fmaxf(a[0], b[0]); r[1] = fmaxf(a[1], b[1]); return r;
}

// ============================================================
// K0: cast feat and W to bf16; init out = bias (for split-K atomics)
// ============================================================
__global__ __launch_bounds__(256) void k_cast(const float* __restrict__ feat,
                                              const float* __restrict__ W,
                                              const float* __restrict__ bias,
                                              unsigned short* __restrict__ featb,
                                              unsigned short* __restrict__ Wb,
                                              float* __restrict__ out) {
    const int b = blockIdx.x;
    const int tid = threadIdx.x;
    if (b >= 2176) {
        // bias-init: rows of out = bias  (1024 blocks x 1024 floats)
        int idx = (b - 2176) * 1024 + tid * 4;
        float4x bv = *(const float4x*)(bias + ((tid * 4) & 255));
        *(float4x*)(out + idx) = bv;
        return;
    }
    const float* src;
    unsigned short* dst;
    int idx;
    if (b < 2048) { src = feat; dst = featb; idx = b * 1024 + tid * 4; }
    else          { src = W;    dst = Wb;    idx = (b - 2048) * 1024 + tid * 4; }
    float4x v = *(const float4x*)(src + idx);
    ushort4 u;
    u.x = f2bf(v[0]); u.y = f2bf(v[1]); u.z = f2bf(v[2]); u.w = f2bf(v[3]);
    *(ushort4*)(dst + idx) = u;
}

// ============================================================
// K1: h = feat @ W^T (bf16 MFMA, 32-row tiles -> 128 blocks)
// epilogue: hT bf16 write + es/ed per-head dots from registers
// -> es + exp tables Bt=exp(ed), Dt=exp(0.2 ed)
// ============================================================
__global__ __launch_bounds__(256) void k_hedge(const unsigned short* __restrict__ featb,
                                               const unsigned short* __restrict__ Wb,
                                               const float* __restrict__ a,
                                               unsigned short* __restrict__ hT,
                                               float* __restrict__ es,
                                               unsigned short* __restrict__ Bt,
                                               unsigned short* __restrict__ Dt) {
    __shared__ __align__(16) unsigned short lds_f[32 * 40];
    __shared__ __align__(16) unsigned short lds_w[256 * 40];
    const int tid  = threadIdx.x;
    const int w    = tid >> 6;
    const int lane = tid & 63;
    const int lidx = lane & 15;
    const int quad = lane >> 4;
    const int i0   = blockIdx.x * 32;
    const int srf  = tid >> 3;          // 0..31
    const int skf  = (tid & 7) * 4;     // 0..28
    const int srw  = tid >> 2;          // 0..63
    const int skw  = (tid & 3) * 8;

    float4x acc[2][4];
    #pragma unroll
    for (int p = 0; p < 2; ++p)
        #pragma unroll
        for (int q = 0; q < 4; ++q)
            acc[p][q] = (float4x){0.f, 0.f, 0.f, 0.f};

    for (int kt = 0; kt < INF_; kt += 32) {
        __syncthreads();
        *(ushort4*)&lds_f[srf * 40 + skf] = *(const ushort4*)&featb[(size_t)(i0 + srf) * INF_ + kt + skf];
        #pragma unroll
        for (int itr = 0; itr < 4; ++itr) {
            int n = itr * 64 + srw;
            *(ushort4*)&lds_w[n * 40 + skw]     = *(const ushort4*)&Wb[(size_t)n * INF_ + kt + skw];
            *(ushort4*)&lds_w[n * 40 + skw + 4] = *(const ushort4*)&Wb[(size_t)n * INF_ + kt + skw + 4];
        }
        __syncthreads();
        short8x af[2], bw[4];
        #pragma unroll
        for (int t = 0; t < 2; ++t)
            af[t] = *(const short8x*)&lds_f[(t * 16 + lidx) * 40 + quad * 8];
        #pragma unroll
        for (int t = 0; t < 4; ++t)
            bw[t] = *(const short8x*)&lds_w[(w * 64 + t * 16 + lidx) * 40 + quad * 8];
        #pragma unroll
        for (int it = 0; it < 2; ++it)
            #pragma unroll
            for (int nt = 0; nt < 4; ++nt)
                acc[it][nt] = __builtin_amdgcn_mfma_f32_16x16x32_bf16(
                    af[it], bw[nt], acc[it][nt], 0, 0, 0);
    }
    // ---- hT write (D layout: col=lane&15 block w*64+nt*16, row=quad*4+r) ----
    #pragma unroll
    for (int it = 0; it < 2; ++it)
        #pragma unroll
        for (int nt = 0; nt < 4; ++nt) {
            int col = w * 64 + nt * 16 + lidx;
            int m0r = i0 + it * 16 + quad * 4;
            uint2 u;
            u.x = cvtpk_bf16(acc[it][nt][0], acc[it][nt][1]);
            u.y = cvtpk_bf16(acc[it][nt][2], acc[it][nt][3]);
            *(uint2*)&hT[(size_t)col * NN + m0r] = u;
        }
    // ---- es/ed epilogue: head = w; col_d = nt*16 + lidx ----
    float asrc[4], adst[4];
    #pragma unroll
    for (int nt = 0; nt < 4; ++nt) {
        asrc[nt] = a[w * 2 * HDIM + nt * 16 + lidx];
        adst[nt] = a[w * 2 * HDIM + HDIM + nt * 16 + lidx];
    }
    #pragma unroll
    for (int it = 0; it < 2; ++it)
        #pragma unroll
        for (int r = 0; r < 4; ++r) {
            float s = 0.f, d = 0.f;
            #pragma unroll
            for (int nt = 0; nt < 4; ++nt) {
                s += acc[it][nt][r] * asrc[nt];
                d += acc[it][nt][r] * adst[nt];
            }
            #pragma unroll
            for (int off = 1; off < 16; off <<= 1) {
                s += __shfl_xor(s, off);
                d += __shfl_xor(d, off);
            }
            if (lidx == 0) {
                int row = i0 + it * 16 + quad * 4 + r;
                es[row * NHEAD + w] = s;
                Bt[row * NHEAD + w] = f2bf(__expf(d));
                Dt[row * NHEAD + w] = f2bf(__expf(0.2f * d));
            }
        }
}

// ============================================================
// K2: fused den + attn-row write. 1 row/block, 4096 blocks.
// Max-trick: exp(leaky(es+ed)) = max(A*b, C*d). Pass 1 computes
// masked per-head terms m_h = mask*max(A*b, C*d) and KEEPS THEM
// IN REGISTERS. Pass 2 is a pure register dot with sc[h] =
// 0.25/den[h] -- zero table re-reads; cvt_pk bf16 pack.
// ============================================================
__global__ __launch_bounds__(256) void k_attn(const float* __restrict__ adj,
                                              const float* __restrict__ es,
                                              const unsigned short* __restrict__ Bt,
                                              const unsigned short* __restrict__ Dt,
                                              unsigned short* __restrict__ attn) {
    __shared__ float red[4][4];
    __shared__ float cfs[4];
    const int tid = threadIdx.x;
    const int wv  = tid >> 6;
    const int lane = tid & 63;
    const int i = blockIdx.x;

    const float4x esv = ((const float4x*)es)[i];
    float2x A01, A23, C01, C23;
    A01[0] = __expf(esv[0]); A01[1] = __expf(esv[1]);
    A23[0] = __expf(esv[2]); A23[1] = __expf(esv[3]);
    C01[0] = __expf(0.2f * esv[0]); C01[1] = __expf(0.2f * esv[1]);
    C23[0] = __expf(0.2f * esv[2]); C23[1] = __expf(0.2f * esv[3]);

    const float4x* arow4 = (const float4x*)(adj + (size_t)i * NN);
    const uint4* B4 = (const uint4*)Bt;
    const uint4* D4 = (const uint4*)Dt;

    // ---- pass 1: masked per-head terms -> registers; accumulate den ----
    float2x m01[4][4], m23[4][4];
    float2x den01 = (float2x){0.f, 0.f};
    float2x den23 = (float2x){0.f, 0.f};
    #pragma unroll
    for (int t = 0; t < 4; ++t) {
        int jv = t * 256 + tid;
        float4x av = arow4[jv];
        uint4 bu0 = B4[jv * 2], bu1 = B4[jv * 2 + 1];
        uint4 du0 = D4[jv * 2], du1 = D4[jv * 2 + 1];
        unsigned int bwv[8] = {bu0.x, bu0.y, bu0.z, bu0.w, bu1.x, bu1.y, bu1.z, bu1.w};
        unsigned int dwv[8] = {du0.x, du0.y, du0.z, du0.w, du1.x, du1.y, du1.z, du1.w};
        #pragma unroll
        for (int u = 0; u < 4; ++u) {
            float2x b01 = bf2up(bwv[u * 2]);
            float2x b23 = bf2up(bwv[u * 2 + 1]);
            float2x d01 = bf2up(dwv[u * 2]);
            float2x d23 = bf2up(dwv[u * 2 + 1]);
            float mf = (av[u] > 0.1f) ? 1.f : 0.f;
            float2x mf2; mf2[0] = mf; mf2[1] = mf;
            m01[t][u] = mf2 * max2(A01 * b01, C01 * d01);
            m23[t][u] = mf2 * max2(A23 * b23, C23 * d23);
            den01 += m01[t][u];
            den23 += m23[t][u];
        }
    }
    float dh[4] = {den01[0], den01[1], den23[0], den23[1]};
    #pragma unroll
    for (int off = 1; off < 64; off <<= 1) {
        #pragma unroll
        for (int h = 0; h < 4; ++h)
            dh[h] += __shfl_xor(dh[h], off);
    }
    if (lane == 0) {
        #pragma unroll
        for (int h = 0; h < 4; ++h) red[wv][h] = dh[h];
    }
    __syncthreads();
    if (tid < 4)
        cfs[tid] = red[0][tid] + red[1][tid] + red[2][tid] + red[3][tid];
    __syncthreads();
    float sc[4];
    #pragma unroll
    for (int h = 0; h < 4; ++h) {
        float den = cfs[h];
        sc[h] = den > 0.f ? 0.25f / den : 0.f;
    }

    // ---- pass 2: pure register dot, cvt_pk pack, store ----
    unsigned short* orow = attn + (size_t)i * NN;
    #pragma unroll
    for (int t = 0; t < 4; ++t) {
        int jv = t * 256 + tid;
        float pv[4];
        #pragma unroll
        for (int u = 0; u < 4; ++u) {
            pv[u] = sc[0] * m01[t][u][0] + sc[1] * m01[t][u][1]
                  + sc[2] * m23[t][u][0] + sc[3] * m23[t][u][1];
        }
        uint2 o;
        o.x = cvtpk_bf16(pv[0], pv[1]);
        o.y = cvtpk_bf16(pv[2], pv[3]);
        *(uint2*)&orow[jv * 4] = o;
    }
}

// ============================================================
// K3: split-K GEMM, LDS-staged (R3 skeleton) with BK=64 and
// conflict-free 72-short pitch. 32-row x 256-col tile, 4 waves.
// Per k-step: 16 MFMA per wave between one barrier pair (2x R3),
// 8 steps per block (half R3's barrier count). Staging: 9x16B
// loads/thread (A: 1 chunk, B: full 128B hT row per thread).
// atomicAdd into bias-initialized out. Grid (128, 8) = 1024 blk.
// LDS 40.5 KB -> 3 blocks/CU.
// ============================================================
__global__ __launch_bounds__(256) void k_out_gemm(const unsigned short* __restrict__ attn,
                                                  const unsigned short* __restrict__ hT,
                                                  float* __restrict__ out) {
    __shared__ __align__(16) unsigned short lds_a[32 * 72];
    __shared__ __align__(16) unsigned short lds_h[256 * 72];
    const int tid  = threadIdx.x;
    const int w    = tid >> 6;
    const int lane = tid & 63;
    const int lidx = lane & 15;
    const int quad = lane >> 4;
    const int i0    = blockIdx.x * 32;
    const int kbase = blockIdx.y * (NN / KSPLIT);   // 512-wide k slice
    const int sar  = tid >> 3;          // A stage row 0..31
    const int sac  = (tid & 7) * 8;     // A stage col (shorts) 0..56

    float4x acc[2][4];
    #pragma unroll
    for (int p = 0; p < 2; ++p)
        #pragma unroll
        for (int q = 0; q < 4; ++q)
            acc[p][q] = (float4x){0.f, 0.f, 0.f, 0.f};

    short8x pa;
    short8x ph[8];
    pa = *(const short8x*)&attn[(size_t)(i0 + sar) * NN + kbase + sac];
    #pragma unroll
    for (int c = 0; c < 8; ++c)
        ph[c] = *(const short8x*)&hT[(size_t)tid * NN + kbase + c * 8];

    const int KSTEPS = (NN / KSPLIT) / 64;   // 8
    for (int ks = 0; ks < KSTEPS; ++ks) {
        __syncthreads();
        *(short8x*)&lds_a[sar * 72 + sac] = pa;
        #pragma unroll
        for (int c = 0; c < 8; ++c)
            *(short8x*)&lds_h[tid * 72 + c * 8] = ph[c];
        __syncthreads();
        if (ks + 1 < KSTEPS) {
            const int ko = kbase + (ks + 1) * 64;
            pa = *(const short8x*)&attn[(size_t)(i0 + sar) * NN + ko + sac];
            #pragma unroll
            for (int c = 0; c < 8; ++c)
                ph[c] = *(const short8x*)&hT[(size_t)tid * NN + ko + c * 8];
        }
        #pragma unroll
        for (int kk = 0; kk < 2; ++kk) {
            short8x af[2], bfr[4];
            #pragma unroll
            for (int it = 0; it < 2; ++it)
                af[it]  = *(const short8x*)&lds_a[(it * 16 + lidx) * 72 + kk * 32 + quad * 8];
            #pragma unroll
            for (int nt = 0; nt < 4; ++nt)
                bfr[nt] = *(const short8x*)&lds_h[(w * 64 + nt * 16 + lidx) * 72 + kk * 32 + quad * 8];
            #pragma unroll
            for (int it = 0; it < 2; ++it)
                #pragma unroll
                for (int nt = 0; nt < 4; ++nt)
                    acc[it][nt] = __builtin_amdgcn_mfma_f32_16x16x32_bf16(
                        af[it], bfr[nt], acc[it][nt], 0, 0, 0);
        }
    }
    #pragma unroll
    for (int it = 0; it < 2; ++it)
        #pragma unroll
        for (int nt = 0; nt < 4; ++nt)
            #pragma unroll
            for (int rr = 0; rr < 4; ++rr) {
                int row = i0 + it * 16 + quad * 4 + rr;
                int col = w * 64 + nt * 16 + lidx;
                unsafeAtomicAdd(&out[(size_t)row * OUTF + col], acc[it][nt][rr]);
            }
}

// ============================================================
extern "C" void kernel_launch(void* const* d_in, const int* in_sizes, int n_in,
                              void* d_out, int out_size, void* d_ws, size_t ws_size,
                              hipStream_t stream) {
    const float* feat = (const float*)d_in[0];   // [4096,512]
    const float* adj  = (const float*)d_in[1];   // [4096,4096]
    const float* W    = (const float*)d_in[2];   // [256,512]
    const float* a    = (const float*)d_in[3];   // [4,128]
    const float* bias = (const float*)d_in[4];   // [256]
    float* out = (float*)d_out;                  // [4096,256] fp32

    char* ws = (char*)d_ws;
    float*          es    = (float*)(ws + 0);                        // 64 KiB
    unsigned short* Btb   = (unsigned short*)(ws + (64u << 10));     // 32 KiB
    unsigned short* Dtb   = (unsigned short*)(ws + (96u << 10));     // 32 KiB
    unsigned short* hT    = (unsigned short*)(ws + (256u << 10));    // 2 MiB
    unsigned short* attn  = (unsigned short*)(ws + (2560u << 10));   // 32 MiB
    unsigned short* featb = (unsigned short*)(ws + (2560u << 10));   // 4 MiB (dead before attn written)
    unsigned short* Wb    = (unsigned short*)(ws + (6656u << 10));   // 256 KiB (dead before attn)

    k_cast      <<<3200,              256, 0, stream>>>(feat, W, bias, featb, Wb, out);
    k_hedge     <<<128,               256, 0, stream>>>(featb, Wb, a, hT, es, Btb, Dtb);
    k_attn      <<<NN,                256, 0, stream>>>(adj, es, Btb, Dtb, attn);
    k_out_gemm  <<<dim3(128, KSPLIT), 256, 0, stream>>>(attn, hT, out);
}

// Round 7
// 172.222 us; speedup vs baseline: 1.2347x; 1.0998x over previous
//
#include <hip/hip_runtime.h>
#include <math.h>

// ---- problem constants ----
#define NN      4096   // nodes
#define INF_    512    // in features
#define OUTF    256    // out features
#define NHEAD   4
#define HDIM    64
#define KSPLIT  8

typedef __attribute__((ext_vector_type(8))) short  short8x;
typedef __attribute__((ext_vector_type(4))) float  float4x;
typedef __attribute__((ext_vector_type(2))) float  float2x;

__device__ __forceinline__ unsigned short f2bf(float x) {
    union { float f; unsigned int u; } c; c.f = x;
    unsigned int r = (c.u + 0x7FFFu + ((c.u >> 16) & 1u)) >> 16;
    return (unsigned short)r;
}
// pack 2 fp32 -> 2 bf16 in one dword (RNE, identical to f2bf)
__device__ __forceinline__ unsigned int cvtpk_bf16(float lo, float hi) {
    unsigned int r;
    asm("v_cvt_pk_bf16_f32 %0, %1, %2" : "=v"(r) : "v"(lo), "v"(hi));
    return r;
}
// unpack a bf16 pair (one dword) into float2 {lo, hi}
__device__ __forceinline__ float2x bf2up(unsigned int u) {
    union { unsigned int x; float f; } lo, hi;
    lo.x = u << 16; hi.x = u & 0xFFFF0000u;
    float2x r; r[0] = lo.f; r[1] = hi.f; return r;
}
__device__ __forceinline__ float2x max2(float2x a, float2x b) {
    float2x r; r[0] = fmaxf(a[0], b[0]); r[1] = fmaxf(a[1], b[1]); return r;
}

// ============================================================
// K0: cast feat and W to bf16; init out = bias (for split-K atomics)
// ============================================================
__global__ __launch_bounds__(256) void k_cast(const float* __restrict__ feat,
                                              const float* __restrict__ W,
                                              const float* __restrict__ bias,
                                              unsigned short* __restrict__ featb,
                                              unsigned short* __restrict__ Wb,
                                              float* __restrict__ out) {
    const int b = blockIdx.x;
    const int tid = threadIdx.x;
    if (b >= 2176) {
        // bias-init: rows of out = bias  (1024 blocks x 1024 floats)
        int idx = (b - 2176) * 1024 + tid * 4;
        float4x bv = *(const float4x*)(bias + ((tid * 4) & 255));
        *(float4x*)(out + idx) = bv;
        return;
    }
    const float* src;
    unsigned short* dst;
    int idx;
    if (b < 2048) { src = feat; dst = featb; idx = b * 1024 + tid * 4; }
    else          { src = W;    dst = Wb;    idx = (b - 2048) * 1024 + tid * 4; }
    float4x v = *(const float4x*)(src + idx);
    ushort4 u;
    u.x = f2bf(v[0]); u.y = f2bf(v[1]); u.z = f2bf(v[2]); u.w = f2bf(v[3]);
    *(ushort4*)(dst + idx) = u;
}

// ============================================================
// K1: h = feat @ W^T (bf16 MFMA, 32-row tiles -> 128 blocks)
// epilogue: hT bf16 write + es/ed per-head dots from registers
// -> es + exp tables Bt=exp(ed), Dt=exp(0.2 ed)
// ============================================================
__global__ __launch_bounds__(256) void k_hedge(const unsigned short* __restrict__ featb,
                                               const unsigned short* __restrict__ Wb,
                                               const float* __restrict__ a,
                                               unsigned short* __restrict__ hT,
                                               float* __restrict__ es,
                                               unsigned short* __restrict__ Bt,
                                               unsigned short* __restrict__ Dt) {
    __shared__ __align__(16) unsigned short lds_f[32 * 40];
    __shared__ __align__(16) unsigned short lds_w[256 * 40];
    const int tid  = threadIdx.x;
    const int w    = tid >> 6;
    const int lane = tid & 63;
    const int lidx = lane & 15;
    const int quad = lane >> 4;
    const int i0   = blockIdx.x * 32;
    const int srf  = tid >> 3;          // 0..31
    const int skf  = (tid & 7) * 4;     // 0..28
    const int srw  = tid >> 2;          // 0..63
    const int skw  = (tid & 3) * 8;

    float4x acc[2][4];
    #pragma unroll
    for (int p = 0; p < 2; ++p)
        #pragma unroll
        for (int q = 0; q < 4; ++q)
            acc[p][q] = (float4x){0.f, 0.f, 0.f, 0.f};

    for (int kt = 0; kt < INF_; kt += 32) {
        __syncthreads();
        *(ushort4*)&lds_f[srf * 40 + skf] = *(const ushort4*)&featb[(size_t)(i0 + srf) * INF_ + kt + skf];
        #pragma unroll
        for (int itr = 0; itr < 4; ++itr) {
            int n = itr * 64 + srw;
            *(ushort4*)&lds_w[n * 40 + skw]     = *(const ushort4*)&Wb[(size_t)n * INF_ + kt + skw];
            *(ushort4*)&lds_w[n * 40 + skw + 4] = *(const ushort4*)&Wb[(size_t)n * INF_ + kt + skw + 4];
        }
        __syncthreads();
        short8x af[2], bw[4];
        #pragma unroll
        for (int t = 0; t < 2; ++t)
            af[t] = *(const short8x*)&lds_f[(t * 16 + lidx) * 40 + quad * 8];
        #pragma unroll
        for (int t = 0; t < 4; ++t)
            bw[t] = *(const short8x*)&lds_w[(w * 64 + t * 16 + lidx) * 40 + quad * 8];
        #pragma unroll
        for (int it = 0; it < 2; ++it)
            #pragma unroll
            for (int nt = 0; nt < 4; ++nt)
                acc[it][nt] = __builtin_amdgcn_mfma_f32_16x16x32_bf16(
                    af[it], bw[nt], acc[it][nt], 0, 0, 0);
    }
    // ---- hT write (D layout: col=lane&15 block w*64+nt*16, row=quad*4+r) ----
    #pragma unroll
    for (int it = 0; it < 2; ++it)
        #pragma unroll
        for (int nt = 0; nt < 4; ++nt) {
            int col = w * 64 + nt * 16 + lidx;
            int m0r = i0 + it * 16 + quad * 4;
            uint2 u;
            u.x = cvtpk_bf16(acc[it][nt][0], acc[it][nt][1]);
            u.y = cvtpk_bf16(acc[it][nt][2], acc[it][nt][3]);
            *(uint2*)&hT[(size_t)col * NN + m0r] = u;
        }
    // ---- es/ed epilogue: head = w; col_d = nt*16 + lidx ----
    float asrc[4], adst[4];
    #pragma unroll
    for (int nt = 0; nt < 4; ++nt) {
        asrc[nt] = a[w * 2 * HDIM + nt * 16 + lidx];
        adst[nt] = a[w * 2 * HDIM + HDIM + nt * 16 + lidx];
    }
    #pragma unroll
    for (int it = 0; it < 2; ++it)
        #pragma unroll
        for (int r = 0; r < 4; ++r) {
            float s = 0.f, d = 0.f;
            #pragma unroll
            for (int nt = 0; nt < 4; ++nt) {
                s += acc[it][nt][r] * asrc[nt];
                d += acc[it][nt][r] * adst[nt];
            }
            #pragma unroll
            for (int off = 1; off < 16; off <<= 1) {
                s += __shfl_xor(s, off);
                d += __shfl_xor(d, off);
            }
            if (lidx == 0) {
                int row = i0 + it * 16 + quad * 4 + r;
                es[row * NHEAD + w] = s;
                Bt[row * NHEAD + w] = f2bf(__expf(d));
                Dt[row * NHEAD + w] = f2bf(__expf(0.2f * d));
            }
        }
}

// ============================================================
// K2: fused den + attn-row write. 1 row/block, 4096 blocks.
// Max-trick: exp(leaky(es+ed)) = max(A*b, C*d). Pass 1 computes
// masked per-head terms m_h = mask*max(A*b, C*d) and KEEPS THEM
// IN REGISTERS. Pass 2 is a pure register dot with sc[h] =
// 0.25/den[h] -- zero table re-reads; cvt_pk bf16 pack.
// ============================================================
__global__ __launch_bounds__(256) void k_attn(const float* __restrict__ adj,
                                              const float* __restrict__ es,
                                              const unsigned short* __restrict__ Bt,
                                              const unsigned short* __restrict__ Dt,
                                              unsigned short* __restrict__ attn) {
    __shared__ float red[4][4];
    __shared__ float cfs[4];
    const int tid = threadIdx.x;
    const int wv  = tid >> 6;
    const int lane = tid & 63;
    const int i = blockIdx.x;

    const float4x esv = ((const float4x*)es)[i];
    float2x A01, A23, C01, C23;
    A01[0] = __expf(esv[0]); A01[1] = __expf(esv[1]);
    A23[0] = __expf(esv[2]); A23[1] = __expf(esv[3]);
    C01[0] = __expf(0.2f * esv[0]); C01[1] = __expf(0.2f * esv[1]);
    C23[0] = __expf(0.2f * esv[2]); C23[1] = __expf(0.2f * esv[3]);

    const float4x* arow4 = (const float4x*)(adj + (size_t)i * NN);
    const uint4* B4 = (const uint4*)Bt;
    const uint4* D4 = (const uint4*)Dt;

    // ---- pass 1: masked per-head terms -> registers; accumulate den ----
    float2x m01[4][4], m23[4][4];
    float2x den01 = (float2x){0.f, 0.f};
    float2x den23 = (float2x){0.f, 0.f};
    #pragma unroll
    for (int t = 0; t < 4; ++t) {
        int jv = t * 256 + tid;
        float4x av = arow4[jv];
        uint4 bu0 = B4[jv * 2], bu1 = B4[jv * 2 + 1];
        uint4 du0 = D4[jv * 2], du1 = D4[jv * 2 + 1];
        unsigned int bwv[8] = {bu0.x, bu0.y, bu0.z, bu0.w, bu1.x, bu1.y, bu1.z, bu1.w};
        unsigned int dwv[8] = {du0.x, du0.y, du0.z, du0.w, du1.x, du1.y, du1.z, du1.w};
        #pragma unroll
        for (int u = 0; u < 4; ++u) {
            float2x b01 = bf2up(bwv[u * 2]);
            float2x b23 = bf2up(bwv[u * 2 + 1]);
            float2x d01 = bf2up(dwv[u * 2]);
            float2x d23 = bf2up(dwv[u * 2 + 1]);
            float mf = (av[u] > 0.1f) ? 1.f : 0.f;
            float2x mf2; mf2[0] = mf; mf2[1] = mf;
            m01[t][u] = mf2 * max2(A01 * b01, C01 * d01);
            m23[t][u] = mf2 * max2(A23 * b23, C23 * d23);
            den01 += m01[t][u];
            den23 += m23[t][u];
        }
    }
    float dh[4] = {den01[0], den01[1], den23[0], den23[1]};
    #pragma unroll
    for (int off = 1; off < 64; off <<= 1) {
        #pragma unroll
        for (int h = 0; h < 4; ++h)
            dh[h] += __shfl_xor(dh[h], off);
    }
    if (lane == 0) {
        #pragma unroll
        for (int h = 0; h < 4; ++h) red[wv][h] = dh[h];
    }
    __syncthreads();
    if (tid < 4)
        cfs[tid] = red[0][tid] + red[1][tid] + red[2][tid] + red[3][tid];
    __syncthreads();
    float sc[4];
    #pragma unroll
    for (int h = 0; h < 4; ++h) {
        float den = cfs[h];
        sc[h] = den > 0.f ? 0.25f / den : 0.f;
    }

    // ---- pass 2: pure register dot, cvt_pk pack, store ----
    unsigned short* orow = attn + (size_t)i * NN;
    #pragma unroll
    for (int t = 0; t < 4; ++t) {
        int jv = t * 256 + tid;
        float pv[4];
        #pragma unroll
        for (int u = 0; u < 4; ++u) {
            pv[u] = sc[0] * m01[t][u][0] + sc[1] * m01[t][u][1]
                  + sc[2] * m23[t][u][0] + sc[3] * m23[t][u][1];
        }
        uint2 o;
        o.x = cvtpk_bf16(pv[0], pv[1]);
        o.y = cvtpk_bf16(pv[2], pv[3]);
        *(uint2*)&orow[jv * 4] = o;
    }
}

// ============================================================
// K3: split-K GEMM, LDS-staged, BK=64, pitch 72 (conflict-free).
// COALESCED staging: 8 threads per 128B row (sr=tid>>3, sc=tid&7)
// -- a wave covers 8 rows = 16 full cachelines per load instr.
// B's 256 rows staged in 8 passes (8 coalesced loads/thread).
// 16 MFMA per wave per barrier pair, 8 k-steps, reg prefetch.
// atomicAdd into bias-initialized out. Grid (128, 8) = 1024 blk.
// LDS 41.3 KB -> 3 blocks/CU.
// ============================================================
__global__ __launch_bounds__(256) void k_out_gemm(const unsigned short* __restrict__ attn,
                                                  const unsigned short* __restrict__ hT,
                                                  float* __restrict__ out) {
    __shared__ __align__(16) unsigned short lds_a[32 * 72];
    __shared__ __align__(16) unsigned short lds_h[256 * 72];
    const int tid  = threadIdx.x;
    const int w    = tid >> 6;
    const int lane = tid & 63;
    const int lidx = lane & 15;
    const int quad = lane >> 4;
    const int i0    = blockIdx.x * 32;
    const int kbase = blockIdx.y * (NN / KSPLIT);   // 512-wide k slice
    const int sr   = tid >> 3;          // stage row-within-group 0..31
    const int sc   = (tid & 7) * 8;     // stage chunk (shorts) 0..56

    float4x acc[2][4];
    #pragma unroll
    for (int p = 0; p < 2; ++p)
        #pragma unroll
        for (int q = 0; q < 4; ++q)
            acc[p][q] = (float4x){0.f, 0.f, 0.f, 0.f};

    short8x pa;
    short8x ph[8];
    pa = *(const short8x*)&attn[(size_t)(i0 + sr) * NN + kbase + sc];
    #pragma unroll
    for (int p = 0; p < 8; ++p)
        ph[p] = *(const short8x*)&hT[(size_t)(p * 32 + sr) * NN + kbase + sc];

    const int KSTEPS = (NN / KSPLIT) / 64;   // 8
    for (int ks = 0; ks < KSTEPS; ++ks) {
        __syncthreads();
        *(short8x*)&lds_a[sr * 72 + sc] = pa;
        #pragma unroll
        for (int p = 0; p < 8; ++p)
            *(short8x*)&lds_h[(p * 32 + sr) * 72 + sc] = ph[p];
        __syncthreads();
        if (ks + 1 < KSTEPS) {
            const int ko = kbase + (ks + 1) * 64;
            pa = *(const short8x*)&attn[(size_t)(i0 + sr) * NN + ko + sc];
            #pragma unroll
            for (int p = 0; p < 8; ++p)
                ph[p] = *(const short8x*)&hT[(size_t)(p * 32 + sr) * NN + ko + sc];
        }
        #pragma unroll
        for (int kk = 0; kk < 2; ++kk) {
            short8x af[2], bfr[4];
            #pragma unroll
            for (int it = 0; it < 2; ++it)
                af[it]  = *(const short8x*)&lds_a[(it * 16 + lidx) * 72 + kk * 32 + quad * 8];
            #pragma unroll
            for (int nt = 0; nt < 4; ++nt)
                bfr[nt] = *(const short8x*)&lds_h[(w * 64 + nt * 16 + lidx) * 72 + kk * 32 + quad * 8];
            #pragma unroll
            for (int it = 0; it < 2; ++it)
                #pragma unroll
                for (int nt = 0; nt < 4; ++nt)
                    acc[it][nt] = __builtin_amdgcn_mfma_f32_16x16x32_bf16(
                        af[it], bfr[nt], acc[it][nt], 0, 0, 0);
        }
    }
    #pragma unroll
    for (int it = 0; it < 2; ++it)
        #pragma unroll
        for (int nt = 0; nt < 4; ++nt)
            #pragma unroll
            for (int rr = 0; rr < 4; ++rr) {
                int row = i0 + it * 16 + quad * 4 + rr;
                int col = w * 64 + nt * 16 + lidx;
                unsafeAtomicAdd(&out[(size_t)row * OUTF + col], acc[it][nt][rr]);
            }
}

// ============================================================
extern "C" void kernel_launch(void* const* d_in, const int* in_sizes, int n_in,
                              void* d_out, int out_size, void* d_ws, size_t ws_size,
                              hipStream_t stream) {
    const float* feat = (const float*)d_in[0];   // [4096,512]
    const float* adj  = (const float*)d_in[1];   // [4096,4096]
    const float* W    = (const float*)d_in[2];   // [256,512]
    const float* a    = (const float*)d_in[3];   // [4,128]
    const float* bias = (const float*)d_in[4];   // [256]
    float* out = (float*)d_out;                  // [4096,256] fp32

    char* ws = (char*)d_ws;
    float*          es    = (float*)(ws + 0);                        // 64 KiB
    unsigned short* Btb   = (unsigned short*)(ws + (64u << 10));     // 32 KiB
    unsigned short* Dtb   = (unsigned short*)(ws + (96u << 10));     // 32 KiB
    unsigned short* hT    = (unsigned short*)(ws + (256u << 10));    // 2 MiB
    unsigned short* attn  = (unsigned short*)(ws + (2560u << 10));   // 32 MiB
    unsigned short* featb = (unsigned short*)(ws + (2560u << 10));   // 4 MiB (dead before attn written)
    unsigned short* Wb    = (unsigned short*)(ws + (6656u << 10));   // 256 KiB (dead before attn)

    k_cast      <<<3200,              256, 0, stream>>>(feat, W, bias, featb, Wb, out);
    k_hedge     <<<128,               256, 0, stream>>>(featb, Wb, a, hT, es, Btb, Dtb);
    k_attn      <<<NN,                256, 0, stream>>>(adj, es, Btb, Dtb, attn);
    k_out_gemm  <<<dim3(128, KSPLIT), 256, 0, stream>>>(attn, hT, out);
}